// Round 4
// baseline (532.300 us; speedup 1.0000x reference)
//
#include <hip/hip_runtime.h>
#include <hip/hip_bf16.h>
#include <stdint.h>

typedef unsigned short ushort_t;
typedef __attribute__((ext_vector_type(8))) short short8;
typedef __attribute__((ext_vector_type(4))) float floatx4;
typedef __attribute__((ext_vector_type(4))) unsigned short ushortx4;

#define N64 4194304LL   // 65536*64

__device__ __forceinline__ ushort_t f2bf(float f) {
    union { float f; unsigned int i; } v; v.f = f;
    unsigned int u = v.i;
    return (ushort_t)((u + 0x7fffu + ((u >> 16) & 1u)) >> 16);
}

// tanh(x) = 1 - 2/(1+e^{2x}); exp overflow -> inf -> 1, underflow -> -1. 6 VALU.
__device__ __forceinline__ float fast_tanh(float x) {
    float e = __expf(2.f * x);
    return 1.f - 2.f / (e + 1.f);
}

#define GLD16(gp, lp) __builtin_amdgcn_global_load_lds( \
    (const __attribute__((address_space(1))) unsigned int*)(gp), \
    (__attribute__((address_space(3))) unsigned int*)(lp), 16, 0, 0)

// LDS layout for MFMA staging: [group(16 rows)][q(k-chunk of 8)][row(16)][8 elem]
// group stride 512 ushorts, q stride 128, row stride 8.
// Staged by GLD16 with srow = wave*16+(lane&15), skoff = (lane>>4)*8 so that
// lane*16B lands exactly at q*256B + fr*16B. Fragment reads are 1024B/wave
// contiguous -> zero bank conflicts.

// ---------------- fused prep: 6 weight transposes + emb cvt, one launch ----------------
__device__ __forceinline__ void tile_transpose(const float* __restrict__ src,
                                               ushort_t* __restrict__ dst,
                                               int K, int M, int bx, int by, int tid,
                                               ushort_t (*tile)[65]) {
    const int m0 = bx * 64, k0 = by * 64;
    const int tr = tid >> 6, tc = tid & 63;
#pragma unroll
    for (int i = 0; i < 16; i++) {
        int kk = i * 4 + tr;
        tile[kk][tc] = f2bf(src[(long)(k0 + kk) * M + m0 + tc]);
    }
    __syncthreads();
#pragma unroll
    for (int i = 0; i < 16; i++) {
        int mm = i * 4 + tr;
        dst[(long)(m0 + mm) * K + k0 + tc] = tile[tc][mm];
    }
}

__global__ void prep_kernel(const float* __restrict__ vq_w1, ushort_t* __restrict__ w1t,
                            const float* __restrict__ vq_w2, ushort_t* __restrict__ w2t,
                            const float* __restrict__ te_w1, ushort_t* __restrict__ te1t,
                            const float* __restrict__ te_w2, ushort_t* __restrict__ te2t,
                            const float* __restrict__ mean_w, ushort_t* __restrict__ mwt,
                            const float* __restrict__ lv_w, ushort_t* __restrict__ lwt,
                            const float* __restrict__ emb, ushort_t* __restrict__ embb) {
    __shared__ ushort_t tile[64][65];
    const int b = blockIdx.x, tid = threadIdx.x;
    if (b < 128)      tile_transpose(vq_w1, w1t, 512, 1024, b & 15, b >> 4, tid, tile);
    else if (b < 144) tile_transpose(vq_w2, w2t, 1024, 64, 0, b - 128, tid, tile);
    else if (b < 160) tile_transpose(te_w1, te1t, 64, 1024, b - 144, 0, tid, tile);
    else if (b < 416) { int l = b - 160; tile_transpose(te_w2, te2t, 1024, 1024, l & 15, l >> 4, tid, tile); }
    else if (b < 432) tile_transpose(mean_w, mwt, 1024, 64, 0, b - 416, tid, tile);
    else if (b < 448) tile_transpose(lv_w, lwt, 1024, 64, 0, b - 432, tid, tile);
    else {
        int i = (b - 448) * 256 + tid;           // 32 blocks x 256 = 8192 float4
        float4 v = ((const float4*)emb)[i];
        ushortx4 o;
        o.x = f2bf(v.x); o.y = f2bf(v.y); o.z = f2bf(v.z); o.w = f2bf(v.w);
        ((ushortx4*)embb)[i] = o;
    }
}

// ---------------- GEMM1: h = tanh(x @ vq_w1 + b1), x fp32 converted in-kernel ----------------
// X [65536,512] fp32; W1t [1024,512] bf16; H [65536,1024] bf16.
// XCD-swizzled 1-D grid (4096): row-panel's 8 col-blocks land on one XCD.
__global__ __launch_bounds__(256, 2) void gemm1_kernel(
    const float* __restrict__ X, const ushort_t* __restrict__ W1t,
    const float* __restrict__ bias, ushort_t* __restrict__ H) {
    const int K = 512, M = 1024;
    __shared__ ushort_t As[128 * 32];
    __shared__ ushort_t Bs[128 * 32];
    const int tid = threadIdx.x, wave = tid >> 6, lane = tid & 63;
    const int bid = blockIdx.x;
    const int xcd = bid & 7, kk = bid >> 3;
    const long row0 = (long)((kk >> 3) * 8 + xcd) * 128;
    const long col0 = (long)(kk & 7) * 128;
    const int fr = lane & 15, q = lane >> 4, kq = q * 8;
    const int srow = wave * 16 + fr, skoff = q * 8;
    const float* aG = X + (row0 + srow) * K + skoff;
    const ushort_t* bG = W1t + (col0 + srow) * K + skoff;
    const int asO = wave * 512 + q * 128 + fr * 8;   // element offset, [g][q][row][8]
    ushort_t* bsW = Bs + wave * 512;
    floatx4 acc[4][4];
#pragma unroll
    for (int i = 0; i < 4; i++)
#pragma unroll
        for (int j = 0; j < 4; j++) acc[i][j] = (floatx4){0.f, 0.f, 0.f, 0.f};
    const int wm = (wave & 1) * 64, wn = (wave >> 1) * 64;
    const int ga = (wave & 1) * 4, gb = (wave >> 1) * 4;
    for (int k0 = 0; k0 < K; k0 += 32) {
        GLD16(bG, bsW);
        GLD16(bG + (long)64 * K, bsW + 2048);
        float4 a0 = *(const float4*)aG;
        float4 a1 = *(const float4*)(aG + 4);
        float4 a2 = *(const float4*)(aG + 64 * K);
        float4 a3 = *(const float4*)(aG + 64 * K + 4);
        short8 s0, s1;
        s0[0] = f2bf(a0.x); s0[1] = f2bf(a0.y); s0[2] = f2bf(a0.z); s0[3] = f2bf(a0.w);
        s0[4] = f2bf(a1.x); s0[5] = f2bf(a1.y); s0[6] = f2bf(a1.z); s0[7] = f2bf(a1.w);
        s1[0] = f2bf(a2.x); s1[1] = f2bf(a2.y); s1[2] = f2bf(a2.z); s1[3] = f2bf(a2.w);
        s1[4] = f2bf(a3.x); s1[5] = f2bf(a3.y); s1[6] = f2bf(a3.z); s1[7] = f2bf(a3.w);
        *(short8*)&As[asO] = s0;
        *(short8*)&As[asO + 2048] = s1;
        aG += 32; bG += 32;
        __syncthreads();
        short8 af[4], bf[4];
#pragma unroll
        for (int i = 0; i < 4; i++) af[i] = *(const short8*)&As[(ga + i) * 512 + q * 128 + fr * 8];
#pragma unroll
        for (int j = 0; j < 4; j++) bf[j] = *(const short8*)&Bs[(gb + j) * 512 + q * 128 + fr * 8];
#pragma unroll
        for (int i = 0; i < 4; i++)
#pragma unroll
            for (int j = 0; j < 4; j++)
                acc[i][j] = __builtin_amdgcn_mfma_f32_16x16x32_bf16(af[i], bf[j], acc[i][j], 0, 0, 0);
        __syncthreads();
    }
    float bj[4];
#pragma unroll
    for (int j = 0; j < 4; j++) bj[j] = bias[col0 + wn + j * 16 + fr];
#pragma unroll
    for (int i = 0; i < 4; i++) {
        const long rb = row0 + wm + i * 16 + q * 4;
#pragma unroll
        for (int r = 0; r < 4; r++) {
            ushort_t* crow = H + (rb + r) * M + col0 + wn + fr;
#pragma unroll
            for (int j = 0; j < 4; j++) crow[j * 16] = f2bf(fast_tanh(acc[i][j][r] + bj[j]));
        }
    }
}

// ---------------- table GEMM: C = tanh(A @ Bt^T + bias), bf16, small grids ----------------
__global__ __launch_bounds__(256, 2) void gemm_bt_kernel(
    const ushort_t* __restrict__ A, const ushort_t* __restrict__ Bt,
    const float* __restrict__ bias, ushort_t* __restrict__ C, int K, int M) {
    __shared__ ushort_t As[128 * 32];
    __shared__ ushort_t Bs[128 * 32];
    const int tid = threadIdx.x, wave = tid >> 6, lane = tid & 63;
    const long row0 = (long)blockIdx.y * 128;
    const long col0 = (long)blockIdx.x * 128;
    const int fr = lane & 15, q = lane >> 4;
    const int srow = wave * 16 + fr, skoff = q * 8;
    const ushort_t* aG = A + (row0 + srow) * K + skoff;
    const ushort_t* bG = Bt + (col0 + srow) * K + skoff;
    ushort_t* asW = As + wave * 512;
    ushort_t* bsW = Bs + wave * 512;
    floatx4 acc[4][4];
#pragma unroll
    for (int i = 0; i < 4; i++)
#pragma unroll
        for (int j = 0; j < 4; j++) acc[i][j] = (floatx4){0.f, 0.f, 0.f, 0.f};
    const int wm = (wave & 1) * 64, wn = (wave >> 1) * 64;
    const int ga = (wave & 1) * 4, gb = (wave >> 1) * 4;
    for (int k0 = 0; k0 < K; k0 += 32) {
        GLD16(aG, asW);
        GLD16(aG + (long)64 * K, asW + 2048);
        GLD16(bG, bsW);
        GLD16(bG + (long)64 * K, bsW + 2048);
        aG += 32; bG += 32;
        __syncthreads();
        short8 af[4], bf[4];
#pragma unroll
        for (int i = 0; i < 4; i++) af[i] = *(const short8*)&As[(ga + i) * 512 + q * 128 + fr * 8];
#pragma unroll
        for (int j = 0; j < 4; j++) bf[j] = *(const short8*)&Bs[(gb + j) * 512 + q * 128 + fr * 8];
#pragma unroll
        for (int i = 0; i < 4; i++)
#pragma unroll
            for (int j = 0; j < 4; j++)
                acc[i][j] = __builtin_amdgcn_mfma_f32_16x16x32_bf16(af[i], bf[j], acc[i][j], 0, 0, 0);
        __syncthreads();
    }
    float bj[4];
#pragma unroll
    for (int j = 0; j < 4; j++) bj[j] = bias[col0 + wn + j * 16 + fr];
#pragma unroll
    for (int i = 0; i < 4; i++) {
        const long rb = row0 + wm + i * 16 + q * 4;
#pragma unroll
        for (int r = 0; r < 4; r++) {
            ushort_t* crow = C + (rb + r) * M + col0 + wn + fr;
#pragma unroll
            for (int j = 0; j < 4; j++) crow[j * 16] = f2bf(fast_tanh(acc[i][j][r] + bj[j]));
        }
    }
}

// ---------------- heads table: mean & log_var over 512 rows, fp32 tables out ----------------
__global__ __launch_bounds__(256, 2) void heads_tab_kernel(
    const ushort_t* __restrict__ A, const ushort_t* __restrict__ Mwt,
    const ushort_t* __restrict__ Lwt, const float* __restrict__ mb,
    const float* __restrict__ lb, float* __restrict__ meanTab,
    float* __restrict__ lvTab) {
    const int K = 1024;
    __shared__ ushort_t As[128 * 32];
    __shared__ ushort_t Bs[128 * 32];
    const int tid = threadIdx.x, wave = tid >> 6, lane = tid & 63;
    const long row0 = (long)blockIdx.x * 128;
    const int fr = lane & 15, q = lane >> 4;
    const int srow = wave * 16 + fr, skoff = q * 8;
    const ushort_t* aG = A + (row0 + srow) * K + skoff;
    const ushort_t* bG0 = Mwt + (long)srow * K + skoff;   // cols 0..63 -> groups 0-3
    const ushort_t* bG1 = Lwt + (long)srow * K + skoff;   // cols 64..127 -> groups 4-7
    ushort_t* asW = As + wave * 512;
    ushort_t* bsW = Bs + wave * 512;
    floatx4 acc[4][4];
#pragma unroll
    for (int i = 0; i < 4; i++)
#pragma unroll
        for (int j = 0; j < 4; j++) acc[i][j] = (floatx4){0.f, 0.f, 0.f, 0.f};
    const int wm = (wave & 1) * 64, wn = (wave >> 1) * 64;
    const int ga = (wave & 1) * 4, gb = (wave >> 1) * 4;
    for (int k0 = 0; k0 < K; k0 += 32) {
        GLD16(aG, asW);
        GLD16(aG + (long)64 * K, asW + 2048);
        GLD16(bG0, bsW);
        GLD16(bG1, bsW + 2048);
        aG += 32; bG0 += 32; bG1 += 32;
        __syncthreads();
        short8 af[4], bf[4];
#pragma unroll
        for (int i = 0; i < 4; i++) af[i] = *(const short8*)&As[(ga + i) * 512 + q * 128 + fr * 8];
#pragma unroll
        for (int j = 0; j < 4; j++) bf[j] = *(const short8*)&Bs[(gb + j) * 512 + q * 128 + fr * 8];
#pragma unroll
        for (int i = 0; i < 4; i++)
#pragma unroll
            for (int j = 0; j < 4; j++)
                acc[i][j] = __builtin_amdgcn_mfma_f32_16x16x32_bf16(af[i], bf[j], acc[i][j], 0, 0, 0);
        __syncthreads();
    }
    float bj[4];
    float* ob[4];
#pragma unroll
    for (int j = 0; j < 4; j++) {
        const int c = wn + j * 16 + fr;   // 0..127
        bj[j] = (c < 64) ? mb[c] : lb[c - 64];
        ob[j] = (c < 64) ? (meanTab + c) : (lvTab + (c - 64));
    }
#pragma unroll
    for (int i = 0; i < 4; i++) {
        const long rb = row0 + wm + i * 16 + q * 4;
#pragma unroll
        for (int r = 0; r < 4; r++) {
#pragma unroll
            for (int j = 0; j < 4; j++) ob[j][(rb + r) * 64] = acc[i][j][r] + bj[j];
        }
    }
}

// ---------------- fused VQ: z-GEMM + argmin + idx out + loss ----------------
__global__ __launch_bounds__(256, 1) void vq_kernel(
    const ushort_t* __restrict__ H, const ushort_t* __restrict__ W2t,
    const float* __restrict__ b2, const float* __restrict__ emb,
    int* __restrict__ idxOut, float* __restrict__ lossAcc) {
    const int K = 1024;
    __shared__ ushort_t As[128 * 32];   // 8KB
    __shared__ ushort_t Bs[64 * 32];    // 4KB
    __shared__ ushort_t zb[128 * 72];   // 18KB  z bf16, row stride 72 (conflict pad)
    __shared__ ushort_t ebc[128 * 72];  // 18KB  codebook chunk bf16, stride 72
    __shared__ float enorm[512];
    __shared__ int ridx[128];
    __shared__ float lred[4];
    const int tid = threadIdx.x, wave = tid >> 6, lane = tid & 63;
    const long row0 = (long)blockIdx.x * 128;
    const int fr = lane & 15, q = lane >> 4, kq = q * 8;
    const int srow = wave * 16 + fr, skoff = q * 8;
    const ushort_t* aG = H + (row0 + srow) * K + skoff;
    const ushort_t* bG = W2t + (long)srow * K + skoff;
    ushort_t* asW = As + wave * 512;
    ushort_t* bsW = Bs + wave * 512;
    floatx4 acc[2][4];
#pragma unroll
    for (int i = 0; i < 2; i++)
#pragma unroll
        for (int j = 0; j < 4; j++) acc[i][j] = (floatx4){0.f, 0.f, 0.f, 0.f};
    const int wr = wave * 32;
    // ---- z = H @ W2t^T + b2 ----
    for (int k0 = 0; k0 < K; k0 += 32) {
        GLD16(aG, asW);
        GLD16(aG + (long)64 * K, asW + 2048);
        GLD16(bG, bsW);
        aG += 32; bG += 32;
        __syncthreads();
        short8 af[2], bf[4];
#pragma unroll
        for (int i = 0; i < 2; i++) af[i] = *(const short8*)&As[(wave * 2 + i) * 512 + q * 128 + fr * 8];
#pragma unroll
        for (int j = 0; j < 4; j++) bf[j] = *(const short8*)&Bs[j * 512 + q * 128 + fr * 8];
#pragma unroll
        for (int i = 0; i < 2; i++)
#pragma unroll
            for (int j = 0; j < 4; j++)
                acc[i][j] = __builtin_amdgcn_mfma_f32_16x16x32_bf16(af[i], bf[j], acc[i][j], 0, 0, 0);
        __syncthreads();
    }
    // add bias, stage z (bf16) for the distance MFMA
#pragma unroll
    for (int j = 0; j < 4; j++) {
        float bb = b2[j * 16 + fr];
#pragma unroll
        for (int i = 0; i < 2; i++)
#pragma unroll
            for (int r = 0; r < 4; r++) {
                acc[i][j][r] += bb;
                zb[(wr + i * 16 + q * 4 + r) * 72 + j * 16 + fr] = f2bf(acc[i][j][r]);
            }
    }
    // codebook squared norms (fp32, from global)
    for (int c = tid; c < 512; c += 256) {
        const float4* e = (const float4*)(emb + c * 64);
        float s = 0.f;
#pragma unroll
        for (int k = 0; k < 16; k++) { float4 v = e[k]; s += v.x * v.x + v.y * v.y + v.z * v.z + v.w * v.w; }
        enorm[c] = s;
    }
    __syncthreads();
    // z fragments (A-operand layout) — rows of this wave
    short8 za[2][2];
#pragma unroll
    for (int i = 0; i < 2; i++)
#pragma unroll
        for (int h = 0; h < 2; h++)
            za[i][h] = *(const short8*)&zb[(wr + i * 16 + fr) * 72 + h * 32 + kq];
    float minv[8]; int mini[8];
#pragma unroll
    for (int t = 0; t < 8; t++) { minv[t] = 3.0e38f; mini[t] = 0; }
    // ---- dist = ||e||^2 - 2 z.e, chunked 128 codes ----
    for (int ch = 0; ch < 4; ch++) {
        __syncthreads();
        const float4* esrc = (const float4*)(emb + ch * 128 * 64);
        for (int g = tid; g < 2048; g += 256) {
            float4 v = esrc[g];
            ushortx4 o;
            o.x = f2bf(v.x); o.y = f2bf(v.y); o.z = f2bf(v.z); o.w = f2bf(v.w);
            *(ushortx4*)&ebc[(g >> 4) * 72 + (g & 15) * 4] = o;
        }
        __syncthreads();
#pragma unroll
        for (int jt = 0; jt < 8; jt++) {
            const int code = ch * 128 + jt * 16 + fr;
            short8 e0 = *(const short8*)&ebc[(jt * 16 + fr) * 72 + kq];
            short8 e1 = *(const short8*)&ebc[(jt * 16 + fr) * 72 + 32 + kq];
            float en = enorm[code];
#pragma unroll
            for (int i = 0; i < 2; i++) {
                floatx4 s = (floatx4){0.f, 0.f, 0.f, 0.f};
                s = __builtin_amdgcn_mfma_f32_16x16x32_bf16(za[i][0], e0, s, 0, 0, 0);
                s = __builtin_amdgcn_mfma_f32_16x16x32_bf16(za[i][1], e1, s, 0, 0, 0);
#pragma unroll
                for (int r = 0; r < 4; r++) {
                    float d = en - 2.f * s[r];
                    int t = i * 4 + r;
                    if (d < minv[t]) { minv[t] = d; mini[t] = code; }
                }
            }
        }
    }
    // argmin across the 16 lanes sharing each output row
#pragma unroll
    for (int m = 1; m < 16; m <<= 1) {
#pragma unroll
        for (int t = 0; t < 8; t++) {
            float ov = __shfl_xor(minv[t], m, 64);
            int oi = __shfl_xor(mini[t], m, 64);
            if (ov < minv[t] || (ov == minv[t] && oi < mini[t])) { minv[t] = ov; mini[t] = oi; }
        }
    }
    if (fr == 0) {
#pragma unroll
        for (int t = 0; t < 8; t++) {
            int row = wr + (t >> 2) * 16 + q * 4 + (t & 3);
            ridx[row] = mini[t];
            idxOut[row0 + row] = mini[t];
        }
    }
    __syncthreads();
    // ---- loss partial: sum (z_q - z)^2, fp32 ----
    float s = 0.f;
#pragma unroll
    for (int i = 0; i < 2; i++)
#pragma unroll
        for (int r = 0; r < 4; r++) {
            int row = wr + i * 16 + q * 4 + r;
            int idx = ridx[row];
#pragma unroll
            for (int j = 0; j < 4; j++) {
                int col = j * 16 + fr;
                float zq = emb[idx * 64 + col];
                float d = zq - acc[i][j][r];
                s += d * d;
            }
        }
#pragma unroll
    for (int m = 1; m < 64; m <<= 1) s += __shfl_xor(s, m, 64);
    if (lane == 0) lred[wave] = s;
    __syncthreads();
    if (tid == 0) atomicAdd(lossAcc, lred[0] + lred[1] + lred[2] + lred[3]);
}

// ---------------- gather: out rows from 512-entry tables ----------------
__global__ void gather_out_kernel(const int* __restrict__ idx,
                                  const float4* __restrict__ meanTab,
                                  const float4* __restrict__ lvTab,
                                  float4* __restrict__ out) {
    int g = blockIdx.x * 256 + threadIdx.x;   // 0 .. 65536*16
    int row = g >> 4, part = g & 15;
    int id = idx[row];
    out[g] = meanTab[id * 16 + part];
    out[1048576 + g] = lvTab[id * 16 + part];   // N64/4 float4 offset
}

__global__ void finish_kernel(const float* __restrict__ lossAcc, float* __restrict__ out) {
    out[0] = lossAcc[0] * (1.f / (65536.f * 32.f));   // 2*sum/(N*64)
}

extern "C" void kernel_launch(void* const* d_in, const int* in_sizes, int n_in,
                              void* d_out, int out_size, void* d_ws, size_t ws_size,
                              hipStream_t stream) {
    const float* x      = (const float*)d_in[0];
    const float* vq_w1  = (const float*)d_in[1];
    const float* vq_b1  = (const float*)d_in[2];
    const float* vq_w2  = (const float*)d_in[3];
    const float* vq_b2  = (const float*)d_in[4];
    const float* emb    = (const float*)d_in[5];
    const float* te_w1  = (const float*)d_in[6];
    const float* te_b1  = (const float*)d_in[7];
    const float* te_w2  = (const float*)d_in[8];
    const float* te_b2  = (const float*)d_in[9];
    const float* mean_w = (const float*)d_in[10];
    const float* mean_b = (const float*)d_in[11];
    const float* lv_w   = (const float*)d_in[12];
    const float* lv_b   = (const float*)d_in[13];
    float* out = (float*)d_out;
    char* ws = (char*)d_ws;
    ushort_t* h       = (ushort_t*)(ws + 0LL);          // 128MB [65536,1024] bf16
    ushort_t* w1t     = (ushort_t*)(ws + 134217728LL);  // 1MB   [1024,512]
    ushort_t* te2t    = (ushort_t*)(ws + 135266304LL);  // 2MB   [1024,1024]
    ushort_t* w2t     = (ushort_t*)(ws + 137363456LL);  // 128KB [64,1024]
    ushort_t* te1t    = (ushort_t*)(ws + 137494528LL);  // 128KB [1024,64]
    ushort_t* mwt     = (ushort_t*)(ws + 137625600LL);  // 128KB [64,1024]
    ushort_t* lwt     = (ushort_t*)(ws + 137756672LL);  // 128KB [64,1024]
    ushort_t* embb    = (ushort_t*)(ws + 137887744LL);  // 64KB  [512,64] bf16
    ushort_t* t1tab   = (ushort_t*)(ws + 137953280LL);  // 1MB   [512,1024] bf16
    ushort_t* t2tab   = (ushort_t*)(ws + 139001856LL);  // 1MB   [512,1024] bf16
    float*    meanTab = (float*)   (ws + 140050432LL);  // 128KB [512,64] fp32
    float*    lvTab   = (float*)   (ws + 140181504LL);  // 128KB [512,64] fp32
    int*      idxbuf  = (int*)     (ws + 140312576LL);  // 256KB [65536] int32
    float*    lossAcc = (float*)   (ws + 140574720LL);  // 4B

    hipMemsetAsync(lossAcc, 0, 4, stream);
    prep_kernel<<<480, 256, 0, stream>>>(vq_w1, w1t, vq_w2, w2t, te_w1, te1t,
                                         te_w2, te2t, mean_w, mwt, lv_w, lwt, emb, embb);
    gemm1_kernel<<<4096, 256, 0, stream>>>(x, w1t, vq_b1, h);
    vq_kernel<<<512, 256, 0, stream>>>(h, w2t, vq_b2, emb, idxbuf, lossAcc);
    gemm_bt_kernel<<<dim3(8, 4), 256, 0, stream>>>(embb, te1t, te_b1, t1tab, 64, 1024);
    gemm_bt_kernel<<<dim3(8, 4), 256, 0, stream>>>(t1tab, te2t, te_b2, t2tab, 1024, 1024);
    heads_tab_kernel<<<4, 256, 0, stream>>>(t2tab, mwt, lwt, mean_b, lv_b, meanTab, lvTab);
    gather_out_kernel<<<4096, 256, 0, stream>>>(idxbuf, (const float4*)meanTab,
                                                (const float4*)lvTab, (float4*)out);
    finish_kernel<<<1, 1, 0, stream>>>(lossAcc, out + 2 * N64);
}

// Round 5
// 485.244 us; speedup vs baseline: 1.0970x; 1.0970x over previous
//
#include <hip/hip_runtime.h>
#include <hip/hip_bf16.h>
#include <stdint.h>

typedef unsigned short ushort_t;
typedef __attribute__((ext_vector_type(8))) short short8;
typedef __attribute__((ext_vector_type(4))) float floatx4;
typedef __attribute__((ext_vector_type(4))) unsigned short ushortx4;

#define N64 4194304LL   // 65536*64

__device__ __forceinline__ ushort_t f2bf(float f) {
    union { float f; unsigned int i; } v; v.f = f;
    unsigned int u = v.i;
    return (ushort_t)((u + 0x7fffu + ((u >> 16) & 1u)) >> 16);
}

// tanh(x) = 1 - 2/(1+e^{2x})
__device__ __forceinline__ float fast_tanh(float x) {
    float e = __expf(2.f * x);
    return 1.f - 2.f / (e + 1.f);
}

#define GLD16(gp, lp) __builtin_amdgcn_global_load_lds( \
    (const __attribute__((address_space(1))) unsigned int*)(gp), \
    (__attribute__((address_space(3))) unsigned int*)(lp), 16, 0, 0)

// LDS staging layout: [group(16 rows)][q(k-chunk of 8)][row(16)][8 elem];
// group stride 512 ushorts. GLD16 dest = base + lane*16B == q*128 + fr*8
// (lane = fr + 16q) -> conflict-free ds_read_b128 frag reads (verified: 0
// SQ_LDS_BANK_CONFLICT in R4).

// ---------------- fused prep: x cvt + 6 transposes + emb cvt + enorm ----------------
__device__ __forceinline__ void tile_transpose(const float* __restrict__ src,
                                               ushort_t* __restrict__ dst,
                                               int K, int M, int bx, int by, int tid,
                                               ushort_t (*tile)[65]) {
    const int m0 = bx * 64, k0 = by * 64;
    const int tr = tid >> 6, tc = tid & 63;
#pragma unroll
    for (int i = 0; i < 16; i++) {
        int kk = i * 4 + tr;
        tile[kk][tc] = f2bf(src[(long)(k0 + kk) * M + m0 + tc]);
    }
    __syncthreads();
#pragma unroll
    for (int i = 0; i < 16; i++) {
        int mm = i * 4 + tr;
        dst[(long)(m0 + mm) * K + k0 + tc] = tile[tc][mm];
    }
}

__global__ void prep_kernel(const float* __restrict__ x, ushort_t* __restrict__ xb,
                            const float* __restrict__ vq_w1, ushort_t* __restrict__ w1t,
                            const float* __restrict__ vq_w2, ushort_t* __restrict__ w2t,
                            const float* __restrict__ te_w1, ushort_t* __restrict__ te1t,
                            const float* __restrict__ te_w2, ushort_t* __restrict__ te2t,
                            const float* __restrict__ mean_w, ushort_t* __restrict__ mwt,
                            const float* __restrict__ lv_w, ushort_t* __restrict__ lwt,
                            const float* __restrict__ emb, ushort_t* __restrict__ embb,
                            float* __restrict__ enormG) {
    __shared__ ushort_t tile[64][65];
    const int b = blockIdx.x, tid = threadIdx.x;
    if (b < 32768) {                       // x fp32 -> bf16, 8.39M float4
        long i = (long)b * 256 + tid;
        float4 v = ((const float4*)x)[i];
        ushortx4 o;
        o.x = f2bf(v.x); o.y = f2bf(v.y); o.z = f2bf(v.z); o.w = f2bf(v.w);
        ((ushortx4*)xb)[i] = o;
    } else if (b < 32896) { int l = b - 32768; tile_transpose(vq_w1, w1t, 512, 1024, l & 15, l >> 4, tid, tile); }
    else if (b < 32912)   { int l = b - 32896; tile_transpose(vq_w2, w2t, 1024, 64, 0, l, tid, tile); }
    else if (b < 32928)   { int l = b - 32912; tile_transpose(te_w1, te1t, 64, 1024, l, 0, tid, tile); }
    else if (b < 33184)   { int l = b - 32928; tile_transpose(te_w2, te2t, 1024, 1024, l & 15, l >> 4, tid, tile); }
    else if (b < 33200)   { int l = b - 33184; tile_transpose(mean_w, mwt, 1024, 64, 0, l, tid, tile); }
    else if (b < 33216)   { int l = b - 33200; tile_transpose(lv_w, lwt, 1024, 64, 0, l, tid, tile); }
    else if (b < 33248) {                  // emb fp32 -> bf16
        int i = (b - 33216) * 256 + tid;   // 8192 float4
        float4 v = ((const float4*)emb)[i];
        ushortx4 o;
        o.x = f2bf(v.x); o.y = f2bf(v.y); o.z = f2bf(v.z); o.w = f2bf(v.w);
        ((ushortx4*)embb)[i] = o;
    } else {                               // codebook squared norms (fp32)
        int c = (b - 33248) * 256 + tid;   // 512 codes
        const float4* e = (const float4*)(emb + c * 64);
        float s = 0.f;
#pragma unroll
        for (int k = 0; k < 16; k++) { float4 v = e[k]; s += v.x * v.x + v.y * v.y + v.z * v.z + v.w * v.w; }
        enormG[c] = s;
    }
}

// ---------------- bf16 GEMM: C = act(A @ Bt^T + bias), all-GLD16 staging ----------------
// swizzled (1-D grid, 8 col-blocks): xcd = bid&7 -> one row-panel's col passes
// stay on one XCD (R3-verified: FETCH 530->45 MB).
__global__ __launch_bounds__(256, 2) void gemm_bt_kernel(
    const ushort_t* __restrict__ A, const ushort_t* __restrict__ Bt,
    const float* __restrict__ bias, ushort_t* __restrict__ C,
    int K, int M, int do_tanh, int swizzled) {
    __shared__ ushort_t As[128 * 32];
    __shared__ ushort_t Bs[128 * 32];
    const int tid = threadIdx.x, wave = tid >> 6, lane = tid & 63;
    long row0, col0;
    if (swizzled) {
        const int bid = blockIdx.x;
        const int xcd = bid & 7, k = bid >> 3;
        row0 = (long)((k >> 3) * 8 + xcd) * 128;
        col0 = (long)(k & 7) * 128;
    } else {
        row0 = (long)blockIdx.y * 128;
        col0 = (long)blockIdx.x * 128;
    }
    const int fr = lane & 15, q = lane >> 4;
    const int srow = wave * 16 + fr, skoff = q * 8;
    const ushort_t* aG = A + (row0 + srow) * K + skoff;
    const ushort_t* bG = Bt + (col0 + srow) * K + skoff;
    ushort_t* asW = As + wave * 512;
    ushort_t* bsW = Bs + wave * 512;
    floatx4 acc[4][4];
#pragma unroll
    for (int i = 0; i < 4; i++)
#pragma unroll
        for (int j = 0; j < 4; j++) acc[i][j] = (floatx4){0.f, 0.f, 0.f, 0.f};
    const int wm = (wave & 1) * 64, wn = (wave >> 1) * 64;
    const int ga = (wave & 1) * 4, gb = (wave >> 1) * 4;
    for (int k0 = 0; k0 < K; k0 += 32) {
        GLD16(aG, asW);
        GLD16(aG + (long)64 * K, asW + 2048);
        GLD16(bG, bsW);
        GLD16(bG + (long)64 * K, bsW + 2048);
        aG += 32; bG += 32;
        __syncthreads();
        short8 af[4], bf[4];
#pragma unroll
        for (int i = 0; i < 4; i++) af[i] = *(const short8*)&As[(ga + i) * 512 + q * 128 + fr * 8];
#pragma unroll
        for (int j = 0; j < 4; j++) bf[j] = *(const short8*)&Bs[(gb + j) * 512 + q * 128 + fr * 8];
#pragma unroll
        for (int i = 0; i < 4; i++)
#pragma unroll
            for (int j = 0; j < 4; j++)
                acc[i][j] = __builtin_amdgcn_mfma_f32_16x16x32_bf16(af[i], bf[j], acc[i][j], 0, 0, 0);
        __syncthreads();
    }
    float bj[4];
#pragma unroll
    for (int j = 0; j < 4; j++) bj[j] = bias[col0 + wn + j * 16 + fr];
#pragma unroll
    for (int i = 0; i < 4; i++) {
        const long rb = row0 + wm + i * 16 + q * 4;
#pragma unroll
        for (int r = 0; r < 4; r++) {
            ushort_t* crow = C + (rb + r) * M + col0 + wn + fr;
#pragma unroll
            for (int j = 0; j < 4; j++) {
                float v = acc[i][j][r] + bj[j];
                if (do_tanh) v = fast_tanh(v);
                crow[j * 16] = f2bf(v);
            }
        }
    }
}

// ---------------- heads table: mean & log_var over 512 rows, fp32 tables out ----------------
__global__ __launch_bounds__(256, 2) void heads_tab_kernel(
    const ushort_t* __restrict__ A, const ushort_t* __restrict__ Mwt,
    const ushort_t* __restrict__ Lwt, const float* __restrict__ mb,
    const float* __restrict__ lb, float* __restrict__ meanTab,
    float* __restrict__ lvTab) {
    const int K = 1024;
    __shared__ ushort_t As[128 * 32];
    __shared__ ushort_t Bs[128 * 32];
    const int tid = threadIdx.x, wave = tid >> 6, lane = tid & 63;
    const long row0 = (long)blockIdx.x * 128;
    const int fr = lane & 15, q = lane >> 4;
    const int srow = wave * 16 + fr, skoff = q * 8;
    const ushort_t* aG = A + (row0 + srow) * K + skoff;
    const ushort_t* bG0 = Mwt + (long)srow * K + skoff;
    const ushort_t* bG1 = Lwt + (long)srow * K + skoff;
    ushort_t* asW = As + wave * 512;
    ushort_t* bsW = Bs + wave * 512;
    floatx4 acc[4][4];
#pragma unroll
    for (int i = 0; i < 4; i++)
#pragma unroll
        for (int j = 0; j < 4; j++) acc[i][j] = (floatx4){0.f, 0.f, 0.f, 0.f};
    const int wm = (wave & 1) * 64, wn = (wave >> 1) * 64;
    const int ga = (wave & 1) * 4, gb = (wave >> 1) * 4;
    for (int k0 = 0; k0 < K; k0 += 32) {
        GLD16(aG, asW);
        GLD16(aG + (long)64 * K, asW + 2048);
        GLD16(bG0, bsW);
        GLD16(bG1, bsW + 2048);
        aG += 32; bG0 += 32; bG1 += 32;
        __syncthreads();
        short8 af[4], bf[4];
#pragma unroll
        for (int i = 0; i < 4; i++) af[i] = *(const short8*)&As[(ga + i) * 512 + q * 128 + fr * 8];
#pragma unroll
        for (int j = 0; j < 4; j++) bf[j] = *(const short8*)&Bs[(gb + j) * 512 + q * 128 + fr * 8];
#pragma unroll
        for (int i = 0; i < 4; i++)
#pragma unroll
            for (int j = 0; j < 4; j++)
                acc[i][j] = __builtin_amdgcn_mfma_f32_16x16x32_bf16(af[i], bf[j], acc[i][j], 0, 0, 0);
        __syncthreads();
    }
    float bj[4];
    float* ob[4];
#pragma unroll
    for (int j = 0; j < 4; j++) {
        const int c = wn + j * 16 + fr;
        bj[j] = (c < 64) ? mb[c] : lb[c - 64];
        ob[j] = (c < 64) ? (meanTab + c) : (lvTab + (c - 64));
    }
#pragma unroll
    for (int i = 0; i < 4; i++) {
        const long rb = row0 + wm + i * 16 + q * 4;
#pragma unroll
        for (int r = 0; r < 4; r++) {
#pragma unroll
            for (int j = 0; j < 4; j++) ob[j][(rb + r) * 64] = acc[i][j][r] + bj[j];
        }
    }
}

// ---------------- fused VQ: z-GEMM + argmin + idx out + loss ----------------
// H [N,1024] bf16; W2t [64,1024] bf16; embb [512,64] bf16; enormG [512] fp32.
__global__ __launch_bounds__(256, 2) void vq_kernel(
    const ushort_t* __restrict__ H, const ushort_t* __restrict__ W2t,
    const float* __restrict__ b2, const float* __restrict__ emb,
    const ushort_t* __restrict__ embb, const float* __restrict__ enormG,
    int* __restrict__ idxOut, float* __restrict__ lossAcc) {
    const int K = 1024;
    __shared__ ushort_t As[128 * 32];   // 8KB
    __shared__ ushort_t Bs[64 * 32];    // 4KB
    __shared__ ushort_t zb[128 * 72];   // 18KB z bf16, stride-72 pad
    __shared__ ushort_t ebc[8 * 1024];  // 16KB codebook chunk, [g][half][q][fr][8]
    __shared__ int ridx[128];
    __shared__ float lred[4];
    const int tid = threadIdx.x, wave = tid >> 6, lane = tid & 63;
    const long row0 = (long)blockIdx.x * 128;
    const int fr = lane & 15, q = lane >> 4, kq = q * 8;
    const int srow = wave * 16 + fr, skoff = q * 8;
    const ushort_t* aG = H + (row0 + srow) * K + skoff;
    const ushort_t* bG = W2t + (long)srow * K + skoff;
    ushort_t* asW = As + wave * 512;
    ushort_t* bsW = Bs + wave * 512;
    floatx4 acc[2][4];
#pragma unroll
    for (int i = 0; i < 2; i++)
#pragma unroll
        for (int j = 0; j < 4; j++) acc[i][j] = (floatx4){0.f, 0.f, 0.f, 0.f};
    const int wr = wave * 32;
    // ---- z = H @ W2t^T + b2 ----
    for (int k0 = 0; k0 < K; k0 += 32) {
        GLD16(aG, asW);
        GLD16(aG + (long)64 * K, asW + 2048);
        GLD16(bG, bsW);
        aG += 32; bG += 32;
        __syncthreads();
        short8 af[2], bf[4];
#pragma unroll
        for (int i = 0; i < 2; i++) af[i] = *(const short8*)&As[(wave * 2 + i) * 512 + q * 128 + fr * 8];
#pragma unroll
        for (int j = 0; j < 4; j++) bf[j] = *(const short8*)&Bs[j * 512 + q * 128 + fr * 8];
#pragma unroll
        for (int i = 0; i < 2; i++)
#pragma unroll
            for (int j = 0; j < 4; j++)
                acc[i][j] = __builtin_amdgcn_mfma_f32_16x16x32_bf16(af[i], bf[j], acc[i][j], 0, 0, 0);
        __syncthreads();
    }
    // add bias, stage z (bf16) in A-operand-readable layout
#pragma unroll
    for (int j = 0; j < 4; j++) {
        float bb = b2[j * 16 + fr];
#pragma unroll
        for (int i = 0; i < 2; i++)
#pragma unroll
            for (int r = 0; r < 4; r++) {
                acc[i][j][r] += bb;
                zb[(wr + i * 16 + q * 4 + r) * 72 + j * 16 + fr] = f2bf(acc[i][j][r]);
            }
    }
    __syncthreads();
    short8 za[2][2];
#pragma unroll
    for (int i = 0; i < 2; i++)
#pragma unroll
        for (int h = 0; h < 2; h++)
            za[i][h] = *(const short8*)&zb[(wr + i * 16 + fr) * 72 + h * 32 + kq];
    float minv[8]; int mini[8];
#pragma unroll
    for (int t = 0; t < 8; t++) { minv[t] = 3.0e38f; mini[t] = 0; }
    // ---- dist = ||e||^2 - 2 z.e, chunks of 128 codes, bf16 codebook via GLD16 ----
    for (int ch = 0; ch < 4; ch++) {
        __syncthreads();   // previous chunk's MFMAs done before restage
        const ushort_t* esrc = embb + (long)(ch * 128) * 64;
        const int g0 = wave * 2;
        GLD16(esrc + (g0 * 16 + fr) * 64 + q * 8,            ebc + g0 * 1024);
        GLD16(esrc + (g0 * 16 + fr) * 64 + 32 + q * 8,       ebc + g0 * 1024 + 512);
        GLD16(esrc + ((g0 + 1) * 16 + fr) * 64 + q * 8,      ebc + (g0 + 1) * 1024);
        GLD16(esrc + ((g0 + 1) * 16 + fr) * 64 + 32 + q * 8, ebc + (g0 + 1) * 1024 + 512);
        __syncthreads();
#pragma unroll
        for (int jt = 0; jt < 8; jt++) {
            const int code = ch * 128 + jt * 16 + fr;
            short8 e0 = *(const short8*)&ebc[jt * 1024 + q * 128 + fr * 8];
            short8 e1 = *(const short8*)&ebc[jt * 1024 + 512 + q * 128 + fr * 8];
            float en = enormG[code];
#pragma unroll
            for (int i = 0; i < 2; i++) {
                floatx4 s = (floatx4){0.f, 0.f, 0.f, 0.f};
                s = __builtin_amdgcn_mfma_f32_16x16x32_bf16(za[i][0], e0, s, 0, 0, 0);
                s = __builtin_amdgcn_mfma_f32_16x16x32_bf16(za[i][1], e1, s, 0, 0, 0);
#pragma unroll
                for (int r = 0; r < 4; r++) {
                    float d = en - 2.f * s[r];
                    int t = i * 4 + r;
                    if (d < minv[t]) { minv[t] = d; mini[t] = code; }
                }
            }
        }
    }
    // argmin across the 16 lanes sharing each output row
#pragma unroll
    for (int m = 1; m < 16; m <<= 1) {
#pragma unroll
        for (int t = 0; t < 8; t++) {
            float ov = __shfl_xor(minv[t], m, 64);
            int oi = __shfl_xor(mini[t], m, 64);
            if (ov < minv[t] || (ov == minv[t] && oi < mini[t])) { minv[t] = ov; mini[t] = oi; }
        }
    }
    if (fr == 0) {
#pragma unroll
        for (int t = 0; t < 8; t++) {
            int row = wr + (t >> 2) * 16 + q * 4 + (t & 3);
            ridx[row] = mini[t];
            idxOut[row0 + row] = mini[t];
        }
    }
    __syncthreads();
    // ---- loss partial: sum (z_q - z)^2, fp32 z in regs, fp32 emb gather (L2-hot) ----
    float s = 0.f;
#pragma unroll
    for (int i = 0; i < 2; i++)
#pragma unroll
        for (int r = 0; r < 4; r++) {
            int row = wr + i * 16 + q * 4 + r;
            int idx = ridx[row];
#pragma unroll
            for (int j = 0; j < 4; j++) {
                int col = j * 16 + fr;
                float zq = emb[idx * 64 + col];
                float d = zq - acc[i][j][r];
                s += d * d;
            }
        }
#pragma unroll
    for (int m = 1; m < 64; m <<= 1) s += __shfl_xor(s, m, 64);
    if (lane == 0) lred[wave] = s;
    __syncthreads();
    if (tid == 0) atomicAdd(lossAcc, lred[0] + lred[1] + lred[2] + lred[3]);
}

// ---------------- gather: out rows from 512-entry tables ----------------
__global__ void gather_out_kernel(const int* __restrict__ idx,
                                  const float4* __restrict__ meanTab,
                                  const float4* __restrict__ lvTab,
                                  float4* __restrict__ out) {
    int g = blockIdx.x * 256 + threadIdx.x;
    int row = g >> 4, part = g & 15;
    int id = idx[row];
    out[g] = meanTab[id * 16 + part];
    out[1048576 + g] = lvTab[id * 16 + part];
}

__global__ void finish_kernel(const float* __restrict__ lossAcc, float* __restrict__ out) {
    out[0] = lossAcc[0] * (1.f / (65536.f * 32.f));   // 2*sum/(N*64)
}

extern "C" void kernel_launch(void* const* d_in, const int* in_sizes, int n_in,
                              void* d_out, int out_size, void* d_ws, size_t ws_size,
                              hipStream_t stream) {
    const float* x      = (const float*)d_in[0];
    const float* vq_w1  = (const float*)d_in[1];
    const float* vq_b1  = (const float*)d_in[2];
    const float* vq_w2  = (const float*)d_in[3];
    const float* vq_b2  = (const float*)d_in[4];
    const float* emb    = (const float*)d_in[5];
    const float* te_w1  = (const float*)d_in[6];
    const float* te_b1  = (const float*)d_in[7];
    const float* te_w2  = (const float*)d_in[8];
    const float* te_b2  = (const float*)d_in[9];
    const float* mean_w = (const float*)d_in[10];
    const float* mean_b = (const float*)d_in[11];
    const float* lv_w   = (const float*)d_in[12];
    const float* lv_b   = (const float*)d_in[13];
    float* out = (float*)d_out;
    char* ws = (char*)d_ws;
    ushort_t* xb      = (ushort_t*)(ws + 0LL);          // 64MB  [65536,512] bf16
    ushort_t* h       = (ushort_t*)(ws + 67108864LL);   // 128MB [65536,1024] bf16
    ushort_t* w1t     = (ushort_t*)(ws + 201326592LL);  // 1MB   [1024,512]
    ushort_t* te2t    = (ushort_t*)(ws + 202375168LL);  // 2MB   [1024,1024]
    ushort_t* w2t     = (ushort_t*)(ws + 204472320LL);  // 128KB [64,1024]
    ushort_t* te1t    = (ushort_t*)(ws + 204603392LL);  // 128KB [1024,64]
    ushort_t* mwt     = (ushort_t*)(ws + 204734464LL);  // 128KB [64,1024]
    ushort_t* lwt     = (ushort_t*)(ws + 204865536LL);  // 128KB [64,1024]
    ushort_t* embb    = (ushort_t*)(ws + 204996608LL);  // 64KB  [512,64] bf16
    ushort_t* t1tab   = (ushort_t*)(ws + 205062144LL);  // 1MB   [512,1024] bf16
    ushort_t* t2tab   = (ushort_t*)(ws + 206110720LL);  // 1MB   [512,1024] bf16
    float*    meanTab = (float*)   (ws + 207159296LL);  // 128KB [512,64] fp32
    float*    lvTab   = (float*)   (ws + 207290368LL);  // 128KB [512,64] fp32
    int*      idxbuf  = (int*)     (ws + 207421440LL);  // 256KB [65536] int32
    float*    enormG  = (float*)   (ws + 207683584LL);  // 2KB   [512] fp32
    float*    lossAcc = (float*)   (ws + 207685632LL);  // 4B

    hipMemsetAsync(lossAcc, 0, 4, stream);
    prep_kernel<<<33250, 256, 0, stream>>>(x, xb, vq_w1, w1t, vq_w2, w2t, te_w1, te1t,
                                           te_w2, te2t, mean_w, mwt, lv_w, lwt,
                                           emb, embb, enormG);
    // GEMM1: h = tanh(xb @ w1t^T + b1), XCD-swizzled
    gemm_bt_kernel<<<4096, 256, 0, stream>>>(xb, w1t, vq_b1, h, 512, 1024, 1, 1);
    vq_kernel<<<512, 256, 0, stream>>>(h, w2t, vq_b2, emb, embb, enormG, idxbuf, lossAcc);
    gemm_bt_kernel<<<dim3(8, 4), 256, 0, stream>>>(embb, te1t, te_b1, t1tab, 64, 1024, 1, 0);
    gemm_bt_kernel<<<dim3(8, 4), 256, 0, stream>>>(t1tab, te2t, te_b2, t2tab, 1024, 1024, 1, 0);
    heads_tab_kernel<<<4, 256, 0, stream>>>(t2tab, mwt, lwt, mean_b, lv_b, meanTab, lvTab);
    gather_out_kernel<<<4096, 256, 0, stream>>>(idxbuf, (const float4*)meanTab,
                                                (const float4*)lvTab, (float4*)out);
    finish_kernel<<<1, 1, 0, stream>>>(lossAcc, out + 2 * N64);
}

// Round 6
// 415.795 us; speedup vs baseline: 1.2802x; 1.1670x over previous
//
#include <hip/hip_runtime.h>
#include <hip/hip_bf16.h>
#include <stdint.h>

typedef unsigned short ushort_t;
typedef __attribute__((ext_vector_type(8))) short short8;
typedef __attribute__((ext_vector_type(4))) float floatx4;
typedef __attribute__((ext_vector_type(4))) unsigned short ushortx4;

#define N64 4194304LL   // 65536*64

__device__ __forceinline__ ushort_t f2bf(float f) {
    union { float f; unsigned int i; } v; v.f = f;
    unsigned int u = v.i;
    return (ushort_t)((u + 0x7fffu + ((u >> 16) & 1u)) >> 16);
}

// tanh(x) = 1 - 2/(1+e^{2x})
__device__ __forceinline__ float fast_tanh(float x) {
    float e = __expf(2.f * x);
    return 1.f - 2.f / (e + 1.f);
}

#define GLD16(gp, lp) __builtin_amdgcn_global_load_lds( \
    (const __attribute__((address_space(1))) unsigned int*)(gp), \
    (__attribute__((address_space(3))) unsigned int*)(lp), 16, 0, 0)

// XOR-swizzled staging (one GLD16 = 16 rows x 64B):
//   lane l -> global row (l>>2), k-chunk (l&3)^((l>>3)&3)   [quad-contiguous 64B]
//   LDS chunk l*16B; frag read (row=fr, kquad=q) at fr*32 + ((q^((fr>>1)&3))*8)
// -> coalesced global (R3-verified pattern) AND conflict-free LDS reads
// (lanes 0-7 cover all 32 banks exactly once; verified by bank arithmetic).

// ---------------- fused prep: x cvt + 6 transposes + emb cvt + enorm ----------------
__device__ __forceinline__ void tile_transpose(const float* __restrict__ src,
                                               ushort_t* __restrict__ dst,
                                               int K, int M, int bx, int by, int tid,
                                               ushort_t (*tile)[65]) {
    const int m0 = bx * 64, k0 = by * 64;
    const int tr = tid >> 6, tc = tid & 63;
#pragma unroll
    for (int i = 0; i < 16; i++) {
        int kk = i * 4 + tr;
        tile[kk][tc] = f2bf(src[(long)(k0 + kk) * M + m0 + tc]);
    }
    __syncthreads();
#pragma unroll
    for (int i = 0; i < 16; i++) {
        int mm = i * 4 + tr;
        dst[(long)(m0 + mm) * K + k0 + tc] = tile[tc][mm];
    }
}

__global__ void prep_kernel(const float* __restrict__ x, ushort_t* __restrict__ xb,
                            const float* __restrict__ vq_w1, ushort_t* __restrict__ w1t,
                            const float* __restrict__ vq_w2, ushort_t* __restrict__ w2t,
                            const float* __restrict__ te_w1, ushort_t* __restrict__ te1t,
                            const float* __restrict__ te_w2, ushort_t* __restrict__ te2t,
                            const float* __restrict__ mean_w, ushort_t* __restrict__ mwt,
                            const float* __restrict__ lv_w, ushort_t* __restrict__ lwt,
                            const float* __restrict__ emb, ushort_t* __restrict__ embb,
                            float* __restrict__ enormG) {
    __shared__ ushort_t tile[64][65];
    const int b = blockIdx.x, tid = threadIdx.x;
    if (b < 32768) {                       // x fp32 -> bf16
        long i = (long)b * 256 + tid;
        float4 v = ((const float4*)x)[i];
        ushortx4 o;
        o.x = f2bf(v.x); o.y = f2bf(v.y); o.z = f2bf(v.z); o.w = f2bf(v.w);
        ((ushortx4*)xb)[i] = o;
    } else if (b < 32896) { int l = b - 32768; tile_transpose(vq_w1, w1t, 512, 1024, l & 15, l >> 4, tid, tile); }
    else if (b < 32912)   { int l = b - 32896; tile_transpose(vq_w2, w2t, 1024, 64, 0, l, tid, tile); }
    else if (b < 32928)   { int l = b - 32912; tile_transpose(te_w1, te1t, 64, 1024, l, 0, tid, tile); }
    else if (b < 33184)   { int l = b - 32928; tile_transpose(te_w2, te2t, 1024, 1024, l & 15, l >> 4, tid, tile); }
    else if (b < 33200)   { int l = b - 33184; tile_transpose(mean_w, mwt, 1024, 64, 0, l, tid, tile); }
    else if (b < 33216)   { int l = b - 33200; tile_transpose(lv_w, lwt, 1024, 64, 0, l, tid, tile); }
    else if (b < 33248) {                  // emb fp32 -> bf16
        int i = (b - 33216) * 256 + tid;
        float4 v = ((const float4*)emb)[i];
        ushortx4 o;
        o.x = f2bf(v.x); o.y = f2bf(v.y); o.z = f2bf(v.z); o.w = f2bf(v.w);
        ((ushortx4*)embb)[i] = o;
    } else {                               // codebook squared norms
        int c = (b - 33248) * 256 + tid;
        const float4* e = (const float4*)(emb + c * 64);
        float s = 0.f;
#pragma unroll
        for (int k = 0; k < 16; k++) { float4 v = e[k]; s += v.x * v.x + v.y * v.y + v.z * v.z + v.w * v.w; }
        enormG[c] = s;
    }
}

// ---------------- bf16 GEMM: C = act(A @ Bt^T + bias), swizzled GLD16 staging ----------------
__global__ __launch_bounds__(256, 2) void gemm_bt_kernel(
    const ushort_t* __restrict__ A, const ushort_t* __restrict__ Bt,
    const float* __restrict__ bias, ushort_t* __restrict__ C,
    int K, int M, int do_tanh, int swizzled) {
    __shared__ ushort_t As[128 * 32];
    __shared__ ushort_t Bs[128 * 32];
    const int tid = threadIdx.x, wave = tid >> 6, lane = tid & 63;
    long row0, col0;
    if (swizzled) {
        const int bid = blockIdx.x;
        const int xcd = bid & 7, k = bid >> 3;
        row0 = (long)((k >> 3) * 8 + xcd) * 128;
        col0 = (long)(k & 7) * 128;
    } else {
        row0 = (long)blockIdx.y * 128;
        col0 = (long)blockIdx.x * 128;
    }
    const int fr = lane & 15, q = lane >> 4;
    // staging: quad-contiguous global, XOR-swizzled LDS content
    const int srow = wave * 16 + (lane >> 2);
    const int skoff = ((lane & 3) ^ ((lane >> 3) & 3)) * 8;
    const ushort_t* aG = A + (row0 + srow) * K + skoff;
    const ushort_t* bG = Bt + (col0 + srow) * K + skoff;
    ushort_t* asW = As + wave * 512;
    ushort_t* bsW = Bs + wave * 512;
    floatx4 acc[4][4];
#pragma unroll
    for (int i = 0; i < 4; i++)
#pragma unroll
        for (int j = 0; j < 4; j++) acc[i][j] = (floatx4){0.f, 0.f, 0.f, 0.f};
    const int wm = (wave & 1) * 64, wn = (wave >> 1) * 64;
    const int ga = (wave & 1) * 4, gb = (wave >> 1) * 4;
    const int fidx = fr * 32 + ((q ^ ((fr >> 1) & 3)) << 3);   // frag read offset
    for (int k0 = 0; k0 < K; k0 += 32) {
        GLD16(aG, asW);
        GLD16(aG + (long)64 * K, asW + 2048);
        GLD16(bG, bsW);
        GLD16(bG + (long)64 * K, bsW + 2048);
        aG += 32; bG += 32;
        __syncthreads();
        short8 af[4], bf[4];
#pragma unroll
        for (int i = 0; i < 4; i++) af[i] = *(const short8*)&As[(ga + i) * 512 + fidx];
#pragma unroll
        for (int j = 0; j < 4; j++) bf[j] = *(const short8*)&Bs[(gb + j) * 512 + fidx];
#pragma unroll
        for (int i = 0; i < 4; i++)
#pragma unroll
            for (int j = 0; j < 4; j++)
                acc[i][j] = __builtin_amdgcn_mfma_f32_16x16x32_bf16(af[i], bf[j], acc[i][j], 0, 0, 0);
        __syncthreads();
    }
    float bj[4];
#pragma unroll
    for (int j = 0; j < 4; j++) bj[j] = bias[col0 + wn + j * 16 + fr];
#pragma unroll
    for (int i = 0; i < 4; i++) {
        const long rb = row0 + wm + i * 16 + q * 4;
#pragma unroll
        for (int r = 0; r < 4; r++) {
            ushort_t* crow = C + (rb + r) * M + col0 + wn + fr;
#pragma unroll
            for (int j = 0; j < 4; j++) {
                float v = acc[i][j][r] + bj[j];
                if (do_tanh) v = fast_tanh(v);
                crow[j * 16] = f2bf(v);
            }
        }
    }
}

// ---------------- heads table: mean & log_var over 512 rows, fp32 tables out ----------------
__global__ __launch_bounds__(256, 2) void heads_tab_kernel(
    const ushort_t* __restrict__ A, const ushort_t* __restrict__ Mwt,
    const ushort_t* __restrict__ Lwt, const float* __restrict__ mb,
    const float* __restrict__ lb, float* __restrict__ meanTab,
    float* __restrict__ lvTab) {
    const int K = 1024;
    __shared__ ushort_t As[128 * 32];
    __shared__ ushort_t Bs[128 * 32];
    const int tid = threadIdx.x, wave = tid >> 6, lane = tid & 63;
    const long row0 = (long)blockIdx.x * 128;
    const int fr = lane & 15, q = lane >> 4;
    const int srow = wave * 16 + (lane >> 2);
    const int skoff = ((lane & 3) ^ ((lane >> 3) & 3)) * 8;
    const ushort_t* aG = A + (row0 + srow) * K + skoff;
    const ushort_t* bG0 = Mwt + (long)srow * K + skoff;
    const ushort_t* bG1 = Lwt + (long)srow * K + skoff;
    ushort_t* asW = As + wave * 512;
    ushort_t* bsW = Bs + wave * 512;
    floatx4 acc[4][4];
#pragma unroll
    for (int i = 0; i < 4; i++)
#pragma unroll
        for (int j = 0; j < 4; j++) acc[i][j] = (floatx4){0.f, 0.f, 0.f, 0.f};
    const int wm = (wave & 1) * 64, wn = (wave >> 1) * 64;
    const int ga = (wave & 1) * 4, gb = (wave >> 1) * 4;
    const int fidx = fr * 32 + ((q ^ ((fr >> 1) & 3)) << 3);
    for (int k0 = 0; k0 < K; k0 += 32) {
        GLD16(aG, asW);
        GLD16(aG + (long)64 * K, asW + 2048);
        GLD16(bG0, bsW);
        GLD16(bG1, bsW + 2048);
        aG += 32; bG0 += 32; bG1 += 32;
        __syncthreads();
        short8 af[4], bf[4];
#pragma unroll
        for (int i = 0; i < 4; i++) af[i] = *(const short8*)&As[(ga + i) * 512 + fidx];
#pragma unroll
        for (int j = 0; j < 4; j++) bf[j] = *(const short8*)&Bs[(gb + j) * 512 + fidx];
#pragma unroll
        for (int i = 0; i < 4; i++)
#pragma unroll
            for (int j = 0; j < 4; j++)
                acc[i][j] = __builtin_amdgcn_mfma_f32_16x16x32_bf16(af[i], bf[j], acc[i][j], 0, 0, 0);
        __syncthreads();
    }
    float bj[4];
    float* ob[4];
#pragma unroll
    for (int j = 0; j < 4; j++) {
        const int c = wn + j * 16 + fr;
        bj[j] = (c < 64) ? mb[c] : lb[c - 64];
        ob[j] = (c < 64) ? (meanTab + c) : (lvTab + (c - 64));
    }
#pragma unroll
    for (int i = 0; i < 4; i++) {
        const long rb = row0 + wm + i * 16 + q * 4;
#pragma unroll
        for (int r = 0; r < 4; r++) {
#pragma unroll
            for (int j = 0; j < 4; j++) ob[j][(rb + r) * 64] = acc[i][j][r] + bj[j];
        }
    }
}

// ---------------- fused VQ: z-GEMM + argmin + idx out + loss ----------------
__global__ __launch_bounds__(256, 2) void vq_kernel(
    const ushort_t* __restrict__ H, const ushort_t* __restrict__ W2t,
    const float* __restrict__ b2, const float* __restrict__ emb,
    const ushort_t* __restrict__ embb, const float* __restrict__ enormG,
    int* __restrict__ idxOut, float* __restrict__ lossAcc) {
    const int K = 1024;
    __shared__ ushort_t As[128 * 32];   // 8KB
    __shared__ ushort_t Bs[64 * 32];    // 4KB
    __shared__ ushort_t zb[128 * 72];   // 18KB z bf16, stride-72 pad
    __shared__ ushort_t ebc[8 * 1024];  // 16KB codebook chunk: [g][half][512]
    __shared__ int ridx[128];
    __shared__ float lred[4];
    const int tid = threadIdx.x, wave = tid >> 6, lane = tid & 63;
    const long row0 = (long)blockIdx.x * 128;
    const int fr = lane & 15, q = lane >> 4, kq = q * 8;
    const int srow = wave * 16 + (lane >> 2);
    const int skoff = ((lane & 3) ^ ((lane >> 3) & 3)) * 8;
    const ushort_t* aG = H + (row0 + srow) * K + skoff;
    const ushort_t* bG = W2t + (long)srow * K + skoff;
    ushort_t* asW = As + wave * 512;
    ushort_t* bsW = Bs + wave * 512;
    floatx4 acc[2][4];
#pragma unroll
    for (int i = 0; i < 2; i++)
#pragma unroll
        for (int j = 0; j < 4; j++) acc[i][j] = (floatx4){0.f, 0.f, 0.f, 0.f};
    const int wr = wave * 32;
    const int fidx = fr * 32 + ((q ^ ((fr >> 1) & 3)) << 3);
    // ---- z = H @ W2t^T + b2 ----
    for (int k0 = 0; k0 < K; k0 += 32) {
        GLD16(aG, asW);
        GLD16(aG + (long)64 * K, asW + 2048);
        GLD16(bG, bsW);
        aG += 32; bG += 32;
        __syncthreads();
        short8 af[2], bf[4];
#pragma unroll
        for (int i = 0; i < 2; i++) af[i] = *(const short8*)&As[(wave * 2 + i) * 512 + fidx];
#pragma unroll
        for (int j = 0; j < 4; j++) bf[j] = *(const short8*)&Bs[j * 512 + fidx];
#pragma unroll
        for (int i = 0; i < 2; i++)
#pragma unroll
            for (int j = 0; j < 4; j++)
                acc[i][j] = __builtin_amdgcn_mfma_f32_16x16x32_bf16(af[i], bf[j], acc[i][j], 0, 0, 0);
        __syncthreads();
    }
    // add bias, stage z (bf16) in A-operand-readable layout
#pragma unroll
    for (int j = 0; j < 4; j++) {
        float bb = b2[j * 16 + fr];
#pragma unroll
        for (int i = 0; i < 2; i++)
#pragma unroll
            for (int r = 0; r < 4; r++) {
                acc[i][j][r] += bb;
                zb[(wr + i * 16 + q * 4 + r) * 72 + j * 16 + fr] = f2bf(acc[i][j][r]);
            }
    }
    __syncthreads();
    short8 za[2][2];
#pragma unroll
    for (int i = 0; i < 2; i++)
#pragma unroll
        for (int h = 0; h < 2; h++)
            za[i][h] = *(const short8*)&zb[(wr + i * 16 + fr) * 72 + h * 32 + kq];
    float minv[8]; int mini[8];
#pragma unroll
    for (int t = 0; t < 8; t++) { minv[t] = 3.0e38f; mini[t] = 0; }
    // ---- dist = ||e||^2 - 2 z.e, chunks of 128 codes, swizzled GLD16 staging ----
    const int er4 = lane >> 2;                         // code within 16-group
    const int ec4 = ((lane & 3) ^ ((lane >> 3) & 3));  // k-chunk (8 elems)
    for (int ch = 0; ch < 4; ch++) {
        __syncthreads();   // previous chunk's MFMAs done before restage
        const ushort_t* esrc = embb + (long)(ch * 128) * 64;
        const int g0 = wave * 2;
        // unit (g,h): 16 codes x 32 elems; dest (g*2+h)*512
        GLD16(esrc + (g0 * 16 + er4) * 64 + ec4 * 8,            ebc + (g0 * 2 + 0) * 512);
        GLD16(esrc + (g0 * 16 + er4) * 64 + 32 + ec4 * 8,       ebc + (g0 * 2 + 1) * 512);
        GLD16(esrc + ((g0 + 1) * 16 + er4) * 64 + ec4 * 8,      ebc + (g0 * 2 + 2) * 512);
        GLD16(esrc + ((g0 + 1) * 16 + er4) * 64 + 32 + ec4 * 8, ebc + (g0 * 2 + 3) * 512);
        __syncthreads();
#pragma unroll
        for (int jt = 0; jt < 8; jt++) {
            const int code = ch * 128 + jt * 16 + fr;
            short8 e0 = *(const short8*)&ebc[(jt * 2 + 0) * 512 + fidx];
            short8 e1 = *(const short8*)&ebc[(jt * 2 + 1) * 512 + fidx];
            float en = enormG[code];
#pragma unroll
            for (int i = 0; i < 2; i++) {
                floatx4 s = (floatx4){0.f, 0.f, 0.f, 0.f};
                s = __builtin_amdgcn_mfma_f32_16x16x32_bf16(za[i][0], e0, s, 0, 0, 0);
                s = __builtin_amdgcn_mfma_f32_16x16x32_bf16(za[i][1], e1, s, 0, 0, 0);
#pragma unroll
                for (int r = 0; r < 4; r++) {
                    float d = en - 2.f * s[r];
                    int t = i * 4 + r;
                    if (d < minv[t]) { minv[t] = d; mini[t] = code; }
                }
            }
        }
    }
    // argmin across the 16 lanes sharing each output row
#pragma unroll
    for (int m = 1; m < 16; m <<= 1) {
#pragma unroll
        for (int t = 0; t < 8; t++) {
            float ov = __shfl_xor(minv[t], m, 64);
            int oi = __shfl_xor(mini[t], m, 64);
            if (ov < minv[t] || (ov == minv[t] && oi < mini[t])) { minv[t] = ov; mini[t] = oi; }
        }
    }
    if (fr == 0) {
#pragma unroll
        for (int t = 0; t < 8; t++) {
            int row = wr + (t >> 2) * 16 + q * 4 + (t & 3);
            ridx[row] = mini[t];
            idxOut[row0 + row] = mini[t];
        }
    }
    __syncthreads();
    // ---- loss partial: sum (z_q - z)^2, fp32 ----
    float s = 0.f;
#pragma unroll
    for (int i = 0; i < 2; i++)
#pragma unroll
        for (int r = 0; r < 4; r++) {
            int row = wr + i * 16 + q * 4 + r;
            int idx = ridx[row];
#pragma unroll
            for (int j = 0; j < 4; j++) {
                int col = j * 16 + fr;
                float zq = emb[idx * 64 + col];
                float d = zq - acc[i][j][r];
                s += d * d;
            }
        }
#pragma unroll
    for (int m = 1; m < 64; m <<= 1) s += __shfl_xor(s, m, 64);
    if (lane == 0) lred[wave] = s;
    __syncthreads();
    if (tid == 0) atomicAdd(lossAcc, lred[0] + lred[1] + lred[2] + lred[3]);
}

// ---------------- gather: out rows from 512-entry tables ----------------
__global__ void gather_out_kernel(const int* __restrict__ idx,
                                  const float4* __restrict__ meanTab,
                                  const float4* __restrict__ lvTab,
                                  float4* __restrict__ out) {
    int g = blockIdx.x * 256 + threadIdx.x;
    int row = g >> 4, part = g & 15;
    int id = idx[row];
    out[g] = meanTab[id * 16 + part];
    out[1048576 + g] = lvTab[id * 16 + part];
}

__global__ void finish_kernel(const float* __restrict__ lossAcc, float* __restrict__ out) {
    out[0] = lossAcc[0] * (1.f / (65536.f * 32.f));   // 2*sum/(N*64)
}

extern "C" void kernel_launch(void* const* d_in, const int* in_sizes, int n_in,
                              void* d_out, int out_size, void* d_ws, size_t ws_size,
                              hipStream_t stream) {
    const float* x      = (const float*)d_in[0];
    const float* vq_w1  = (const float*)d_in[1];
    const float* vq_b1  = (const float*)d_in[2];
    const float* vq_w2  = (const float*)d_in[3];
    const float* vq_b2  = (const float*)d_in[4];
    const float* emb    = (const float*)d_in[5];
    const float* te_w1  = (const float*)d_in[6];
    const float* te_b1  = (const float*)d_in[7];
    const float* te_w2  = (const float*)d_in[8];
    const float* te_b2  = (const float*)d_in[9];
    const float* mean_w = (const float*)d_in[10];
    const float* mean_b = (const float*)d_in[11];
    const float* lv_w   = (const float*)d_in[12];
    const float* lv_b   = (const float*)d_in[13];
    float* out = (float*)d_out;
    char* ws = (char*)d_ws;
    ushort_t* xb      = (ushort_t*)(ws + 0LL);          // 64MB  [65536,512] bf16
    ushort_t* h       = (ushort_t*)(ws + 67108864LL);   // 128MB [65536,1024] bf16
    ushort_t* w1t     = (ushort_t*)(ws + 201326592LL);  // 1MB   [1024,512]
    ushort_t* te2t    = (ushort_t*)(ws + 202375168LL);  // 2MB   [1024,1024]
    ushort_t* w2t     = (ushort_t*)(ws + 204472320LL);  // 128KB [64,1024]
    ushort_t* te1t    = (ushort_t*)(ws + 204603392LL);  // 128KB [1024,64]
    ushort_t* mwt     = (ushort_t*)(ws + 204734464LL);  // 128KB [64,1024]
    ushort_t* lwt     = (ushort_t*)(ws + 204865536LL);  // 128KB [64,1024]
    ushort_t* embb    = (ushort_t*)(ws + 204996608LL);  // 64KB  [512,64] bf16
    ushort_t* t1tab   = (ushort_t*)(ws + 205062144LL);  // 1MB   [512,1024] bf16
    ushort_t* t2tab   = (ushort_t*)(ws + 206110720LL);  // 1MB   [512,1024] bf16
    float*    meanTab = (float*)   (ws + 207159296LL);  // 128KB [512,64] fp32
    float*    lvTab   = (float*)   (ws + 207290368LL);  // 128KB [512,64] fp32
    int*      idxbuf  = (int*)     (ws + 207421440LL);  // 256KB [65536] int32
    float*    enormG  = (float*)   (ws + 207683584LL);  // 2KB   [512] fp32
    float*    lossAcc = (float*)   (ws + 207685632LL);  // 4B

    hipMemsetAsync(lossAcc, 0, 4, stream);
    prep_kernel<<<33250, 256, 0, stream>>>(x, xb, vq_w1, w1t, vq_w2, w2t, te_w1, te1t,
                                           te_w2, te2t, mean_w, mwt, lv_w, lwt,
                                           emb, embb, enormG);
    // GEMM1: h = tanh(xb @ w1t^T + b1), XCD-swizzled
    gemm_bt_kernel<<<4096, 256, 0, stream>>>(xb, w1t, vq_b1, h, 512, 1024, 1, 1);
    vq_kernel<<<512, 256, 0, stream>>>(h, w2t, vq_b2, emb, embb, enormG, idxbuf, lossAcc);
    gemm_bt_kernel<<<dim3(8, 4), 256, 0, stream>>>(embb, te1t, te_b1, t1tab, 64, 1024, 1, 0);
    gemm_bt_kernel<<<dim3(8, 4), 256, 0, stream>>>(t1tab, te2t, te_b2, t2tab, 1024, 1024, 1, 0);
    heads_tab_kernel<<<4, 256, 0, stream>>>(t2tab, mwt, lwt, mean_b, lv_b, meanTab, lvTab);
    gather_out_kernel<<<4096, 256, 0, stream>>>(idxbuf, (const float4*)meanTab,
                                                (const float4*)lvTab, (float4*)out);
    finish_kernel<<<1, 1, 0, stream>>>(lossAcc, out + 2 * N64);
}